// Round 8
// baseline (128.863 us; speedup 1.0000x reference)
//
#include <hip/hip_runtime.h>
#include <math.h>

namespace {
constexpr int B = 2;
constexpr int N = 16384;
constexpr int M = 4096;
constexpr int K = 11;
constexpr int TQ = 64;              // lanes per query group = full wave
constexpr int BLOCK = 512;          // 8 waves/block; 256 blocks -> 1 block/CU
constexpr int Q = 16;               // queries per thread (per wave)
constexpr int GROUPS = BLOCK / TQ;  // 8 waves/block
constexpr int QPB = GROUPS * Q;     // 128 queries/block
constexpr int S = M / TQ;           // 64 candidates per lane
constexpr int CAP = 48;             // per-query collect capacity
}

// Shifted squared distance: |s|^2 - 2 p.s (order preserving). MUST be the
// identical op sequence in phases A/B/C for bit-exact threshold agreement.
__device__ __forceinline__ float d2of(const float4 s, float m2x, float m2y, float m2z) {
  return fmaf(m2x, s.x, fmaf(m2y, s.y, fmaf(m2z, s.z, s.w)));
}

__global__ __launch_bounds__(BLOCK, 2) void voroloss_kernel(
    const float* __restrict__ points,    // [B, N, 3]
    const float* __restrict__ spoints,   // [B, M, 3]
    float* __restrict__ out)             // [B, N]
{
  __shared__ float4 s4[M];                  // (x,y,z,|s|^2) 64 KiB
  __shared__ unsigned short buf[QPB][CAP];  // candidate idx 12 KiB
  __shared__ int cnt[QPB];
  __shared__ int bestb[QPB];                // float bits of running min (sq>=0)

  const int blocks_per_batch = N / QPB;     // 128
  const int b = blockIdx.x / blocks_per_batch;
  const int tile = blockIdx.x % blocks_per_batch;
  const int tid = (int)threadIdx.x;
  const int wl = tid & 63;                  // lane in wave = lane in group
  const int g = tid >> 6;                   // wave id = group id

  const float* sp = spoints + (size_t)b * M * 3;
  for (int j = tid; j < M; j += BLOCK) {
    float x = sp[j * 3 + 0], y = sp[j * 3 + 1], z = sp[j * 3 + 2];
    s4[j] = make_float4(x, y, z, x * x + y * y + z * z);
  }
  if (tid < QPB) { cnt[tid] = 0; bestb[tid] = 0x7f800000; }
  __syncthreads();

  float m2x[Q], m2y[Q], m2z[Q];
#pragma unroll
  for (int q = 0; q < Q; ++q) {
    int n = tile * QPB + q * GROUPS + g;    // same for all lanes of this wave
    m2x[q] = -2.0f * points[((size_t)b * N + n) * 3 + 0];
    m2y[q] = -2.0f * points[((size_t)b * N + n) * 3 + 1];
    m2z[q] = -2.0f * points[((size_t)b * N + n) * 3 + 2];
  }

  // ---- Phase A: per-lane min over strided subset j = i*64 + wl.
  float t0[Q];
#pragma unroll
  for (int q = 0; q < Q; ++q) t0[q] = INFINITY;

  for (int i0 = 0; i0 < S; i0 += 8) {
    float4 sv[8];
#pragma unroll
    for (int c = 0; c < 8; ++c) sv[c] = s4[(i0 + c) * TQ + wl];
#pragma unroll
    for (int q = 0; q < Q; ++q) {
#pragma unroll
      for (int c = 0; c < 8; ++c) {
        t0[q] = fminf(t0[q], d2of(sv[c], m2x[q], m2y[q], m2z[q]));
      }
    }
  }

  // ---- theta[q]: pre-min across xor-32 (-> 32 cells of 128 cands, both wave
  // halves identical), then R7-validated bitonic sort-32, take rank 10.
  // Provable upper bound on the true 11th smallest; guarantees >= 11 collected.
  float theta[Q];
  const int h = wl & 31;
#pragma unroll
  for (int q = 0; q < Q; ++q) {
    float x = fminf(t0[q], __shfl_xor(t0[q], 32));
#pragma unroll
    for (int k = 2; k <= 32; k <<= 1) {
#pragma unroll
      for (int j = 16; j > 0; j >>= 1) {
        if (j < k) {
          float o = __shfl_xor(x, j);
          bool up = (h & k) == 0;
          bool lower = (h & j) == 0;
          x = (lower == up) ? fminf(x, o) : fmaxf(x, o);
        }
      }
    }
    theta[q] = __shfl(x, 10, 64);
  }

  // ---- Phase B: rescan; first hit per (lane,q) kept in a register, 2nd+ hits
  // (rare, ~1/query) pushed immediately. Flush at the end with one ballot +
  // one atomic per query. Buffer order is arbitrary (rank-based C).
  int hidx[Q];
#pragma unroll
  for (int q = 0; q < Q; ++q) hidx[q] = -1;

  for (int i0 = 0; i0 < S; i0 += 4) {
    float4 sv[4];
#pragma unroll
    for (int c = 0; c < 4; ++c) sv[c] = s4[(i0 + c) * TQ + wl];
#pragma unroll
    for (int q = 0; q < Q; ++q) {
      const int qq = q * GROUPS + g;
#pragma unroll
      for (int c = 0; c < 4; ++c) {
        float d = d2of(sv[c], m2x[q], m2y[q], m2z[q]);
        if (d <= theta[q]) {
          int j = (i0 + c) * TQ + wl;
          if (hidx[q] < 0) {
            hidx[q] = j;
          } else {
            int p = atomicAdd(&cnt[qq], 1);
            if (p < CAP) buf[qq][p] = (unsigned short)j;
          }
        }
      }
    }
  }
#pragma unroll
  for (int q = 0; q < Q; ++q) {
    const int qq = q * GROUPS + g;
    bool have = hidx[q] >= 0;
    unsigned long long mb = __ballot(have);
    int total = __popcll(mb);
    int prefix = __popcll(mb & ((1ull << wl) - 1ull));
    int base = 0;
    if (wl == 0 && total > 0) base = atomicAdd(&cnt[qq], total);
    base = __builtin_amdgcn_readfirstlane(base);
    int pos = base + prefix;
    if (have && pos < CAP) buf[qq][pos] = (unsigned short)hidx[q];
  }

  // ---- Phase C: exact selection (lex (d2, idx) = stable top_k). Lane wl owns
  // buffer slot wl (c <= 48 <= 64). Rank = #{entries lex-smaller}.
#pragma unroll
  for (int q = 0; q < Q; ++q) {
    const int qq = q * GROUPS + g;
    int c = __builtin_amdgcn_readfirstlane(cnt[qq]);
    c = c < CAP ? c : CAP;

    bool v = wl < c;
    int ide = (int)buf[qq][v ? wl : 0];
    float4 se = s4[ide];
    float d2e = v ? d2of(se, m2x[q], m2y[q], m2z[q]) : INFINITY;
    ide = v ? ide : 0x7fffffff;

    int rank = 0;
    int f = 0;
    for (; f + 4 <= c; f += 4) {            // 4 uniform entries per b64 read,
      ushort4 e4 = *(const ushort4*)&buf[qq][f];  // 4 independent s4 reads
      int i0_ = e4.x, i1_ = e4.y, i2_ = e4.z, i3_ = e4.w;
      float4 s0 = s4[i0_], s1 = s4[i1_], s2 = s4[i2_], s3 = s4[i3_];
      float d0 = d2of(s0, m2x[q], m2y[q], m2z[q]);
      float d1 = d2of(s1, m2x[q], m2y[q], m2z[q]);
      float d2_ = d2of(s2, m2x[q], m2y[q], m2z[q]);
      float d3 = d2of(s3, m2x[q], m2y[q], m2z[q]);
      rank += ((d0 < d2e) || (d0 == d2e && i0_ < ide)) ? 1 : 0;
      rank += ((d1 < d2e) || (d1 == d2e && i1_ < ide)) ? 1 : 0;
      rank += ((d2_ < d2e) || (d2_ == d2e && i2_ < ide)) ? 1 : 0;
      rank += ((d3 < d2e) || (d3 == d2e && i3_ < ide)) ? 1 : 0;
    }
    for (; f < c; ++f) {
      int if_ = (int)buf[qq][f];
      float4 sf = s4[if_];
      float df = d2of(sf, m2x[q], m2y[q], m2z[q]);
      rank += ((df < d2e) || (df == d2e && if_ < ide)) ? 1 : 0;
    }

    // center = rank 0 (exists, unique): locate lane via ballot, shfl its idx.
    unsigned long long cb = __ballot(v && rank == 0);
    int cl = (int)__builtin_ctzll(cb);
    int ci = __shfl(ide, cl, 64);
    float4 cc = s4[ci];
    float px = -0.5f * m2x[q], py = -0.5f * m2y[q], pz = -0.5f * m2z[q];
    float vx = px - cc.x, vy = py - cc.y, vz = pz - cc.z;

    // edges = ranks 1..10 (exactly 10 since c >= 11).
    // sq = (dot(v,e) - |e|^2/2)^2 / |e|^2  (>= 0, so int-bits atomicMin works)
    bool isedge = v && (rank >= 1) && (rank <= 10);
    float ex = se.x - cc.x, ey = se.y - cc.y, ez = se.z - cc.z;
    float el2 = ex * ex;
    el2 = fmaf(ey, ey, el2);
    el2 = fmaf(ez, ez, el2);
    float dv = vx * ex;
    dv = fmaf(vy, ey, dv);
    dv = fmaf(vz, ez, dv);
    float tt = fmaf(-0.5f, el2, dv);
    float sq = tt * tt * __builtin_amdgcn_rcpf(el2);
    if (isedge) atomicMin(&bestb[qq], __float_as_int(sq));
    int bb = bestb[qq];   // same-address read after atomic: in-order within wave
    if (wl == 0) out[(size_t)b * N + (tile * QPB + q * GROUPS + g)] = __int_as_float(bb);
  }
}

extern "C" void kernel_launch(void* const* d_in, const int* in_sizes, int n_in,
                              void* d_out, int out_size, void* d_ws, size_t ws_size,
                              hipStream_t stream) {
  const float* points = (const float*)d_in[0];
  const float* spoints = (const float*)d_in[1];
  float* out = (float*)d_out;
  (void)in_sizes; (void)n_in; (void)out_size; (void)d_ws; (void)ws_size;
  voroloss_kernel<<<dim3(B * (N / QPB)), dim3(BLOCK), 0, stream>>>(points, spoints, out);
}

// Round 9
// 107.867 us; speedup vs baseline: 1.1946x; 1.1946x over previous
//
#include <hip/hip_runtime.h>
#include <math.h>

namespace {
constexpr int B = 2;
constexpr int N = 16384;
constexpr int M = 4096;
constexpr int K = 11;
constexpr int TQ = 64;              // lanes per query group = full wave
constexpr int BLOCK = 512;          // 8 waves/block
constexpr int Q = 8;                // queries per wave
constexpr int GROUPS = BLOCK / TQ;  // 8 waves/block
constexpr int QPB = GROUPS * Q;     // 64 queries/block -> 512 blocks = 2/CU
constexpr int S = M / TQ;           // 64 candidates per lane
constexpr int CAP = 64;             // one slot per lane
}

// Shifted squared distance: |s|^2 - 2 p.s (order preserving). MUST be the
// identical op sequence in phases A/B/C for bit-exact threshold agreement.
__device__ __forceinline__ float d2of(const float4 s, float m2x, float m2y, float m2z) {
  return fmaf(m2x, s.x, fmaf(m2y, s.y, fmaf(m2z, s.z, s.w)));
}

__global__ __launch_bounds__(BLOCK, 4) void voroloss_kernel(
    const float* __restrict__ points,    // [B, N, 3]
    const float* __restrict__ spoints,   // [B, M, 3]
    float* __restrict__ out)             // [B, N]
{
  __shared__ float4 s4[M];                  // (x,y,z,|s|^2) 64 KiB
  __shared__ unsigned short buf[QPB][CAP];  // candidate idx 8 KiB
  __shared__ int cnt[QPB];

  const int blocks_per_batch = N / QPB;     // 256
  const int b = blockIdx.x / blocks_per_batch;
  const int tile = blockIdx.x % blocks_per_batch;
  const int tid = (int)threadIdx.x;
  const int wl = tid & 63;                  // lane in wave = lane in group
  const int g = tid >> 6;                   // wave id = group id

  const float* sp = spoints + (size_t)b * M * 3;
  for (int j = tid; j < M; j += BLOCK) {
    float x = sp[j * 3 + 0], y = sp[j * 3 + 1], z = sp[j * 3 + 2];
    s4[j] = make_float4(x, y, z, x * x + y * y + z * z);
  }
  if (tid < QPB) cnt[tid] = 0;
  __syncthreads();

  float m2x[Q], m2y[Q], m2z[Q];
#pragma unroll
  for (int q = 0; q < Q; ++q) {
    int n = tile * QPB + q * GROUPS + g;    // uniform per wave
    m2x[q] = -2.0f * points[((size_t)b * N + n) * 3 + 0];
    m2y[q] = -2.0f * points[((size_t)b * N + n) * 3 + 1];
    m2z[q] = -2.0f * points[((size_t)b * N + n) * 3 + 2];
  }

  // ---- Phase A: per-lane min over strided subset j = i*64 + wl.
  // Each ds_read_b128 batch serves all 8 queries; 1024B contiguous per read.
  float t0[Q];
#pragma unroll
  for (int q = 0; q < Q; ++q) t0[q] = INFINITY;

#pragma unroll 2
  for (int i0 = 0; i0 < S; i0 += 8) {
    float4 sv[8];
#pragma unroll
    for (int c = 0; c < 8; ++c) sv[c] = s4[(i0 + c) * TQ + wl];
#pragma unroll
    for (int q = 0; q < Q; ++q) {
#pragma unroll
      for (int c = 0; c < 8; ++c) {
        t0[q] = fminf(t0[q], d2of(sv[c], m2x[q], m2y[q], m2z[q]));
      }
    }
  }

  // ---- theta[q] = 11th smallest of the 32 pair-minima (64 lane minima
  // pre-minned across xor-32, then bitonic sort-32 in each half; both halves
  // identical). Order stat of a 32-value sub-multiset of the true d2 values
  // >= true 11th smallest -> provable upper bound. (R8-validated path.)
  float theta[Q];
  const int h = wl & 31;
#pragma unroll
  for (int q = 0; q < Q; ++q) {
    float x = fminf(t0[q], __shfl_xor(t0[q], 32));
#pragma unroll
    for (int k = 2; k <= 32; k <<= 1) {
#pragma unroll
      for (int j = 16; j > 0; j >>= 1) {
        if (j < k) {
          float o = __shfl_xor(x, j);
          bool up = (h & k) == 0;
          bool lower = (h & j) == 0;
          x = (lower == up) ? fminf(x, o) : fmaxf(x, o);
        }
      }
    }
    theta[q] = __shfl(x, 10, 64);
  }

  // ---- Phase B: rescan; first hit per (lane,q) held in a register, rare 2nd+
  // hits pushed via atomic. One ballot+atomic flush per query at the end.
  int hidx[Q];
#pragma unroll
  for (int q = 0; q < Q; ++q) hidx[q] = -1;

#pragma unroll 2
  for (int i0 = 0; i0 < S; i0 += 8) {
    float4 sv[8];
#pragma unroll
    for (int c = 0; c < 8; ++c) sv[c] = s4[(i0 + c) * TQ + wl];
#pragma unroll
    for (int q = 0; q < Q; ++q) {
      const int qq = q * GROUPS + g;
#pragma unroll
      for (int c = 0; c < 8; ++c) {
        float d = d2of(sv[c], m2x[q], m2y[q], m2z[q]);
        if (d <= theta[q]) {
          int j = (i0 + c) * TQ + wl;
          if (hidx[q] < 0) {
            hidx[q] = j;
          } else {
            int p = atomicAdd(&cnt[qq], 1);
            if (p < CAP) buf[qq][p] = (unsigned short)j;
          }
        }
      }
    }
  }
#pragma unroll
  for (int q = 0; q < Q; ++q) {
    const int qq = q * GROUPS + g;
    bool have = hidx[q] >= 0;
    unsigned long long mb = __ballot(have);
    int total = __popcll(mb);
    int prefix = __popcll(mb & ((1ull << wl) - 1ull));
    int base = 0;
    if (wl == 0 && total > 0) base = atomicAdd(&cnt[qq], total);
    base = __builtin_amdgcn_readfirstlane(base);
    int pos = base + prefix;
    if (have && pos < CAP) buf[qq][pos] = (unsigned short)hidx[q];
  }

  // ---- Phase C: exact selection (lex (d2,idx) = stable top_k). Lane wl owns
  // slot wl; ranks via shfl (no dependent-LDS chains).
#pragma unroll
  for (int q = 0; q < Q; ++q) {
    const int qq = q * GROUPS + g;
    int c = cnt[qq];
    c = c < CAP ? c : CAP;

    bool v = wl < c;
    int ide = (int)buf[qq][v ? wl : 0];
    float4 se = s4[ide];
    float d2e = v ? d2of(se, m2x[q], m2y[q], m2z[q]) : INFINITY;
    ide = v ? ide : 0x7fffffff;

    int rank = 0;
    for (int f = 0; f < c; ++f) {
      float df = __shfl(d2e, f, 64);
      int jf = __shfl(ide, f, 64);
      rank += ((df < d2e) || (df == d2e && jf < ide)) ? 1 : 0;
    }

    // center = rank 0 (exists, unique): ballot + shfl its index.
    unsigned long long cb = __ballot(v && rank == 0);
    int cl = (int)__builtin_ctzll(cb);
    int ci = __shfl(ide, cl, 64);
    float4 cc = s4[ci];
    float px = -0.5f * m2x[q], py = -0.5f * m2y[q], pz = -0.5f * m2z[q];
    float vx = px - cc.x, vy = py - cc.y, vz = pz - cc.z;

    // edges = ranks 1..10 (exactly 10 since c >= 11).
    // sq = (dot(v,e) - |e|^2/2)^2 / |e|^2
    bool isedge = v && (rank >= 1) && (rank <= 10);
    float ex = se.x - cc.x, ey = se.y - cc.y, ez = se.z - cc.z;
    float el2 = ex * ex;
    el2 = fmaf(ey, ey, el2);
    el2 = fmaf(ez, ez, el2);
    float dv = vx * ex;
    dv = fmaf(vy, ey, dv);
    dv = fmaf(vz, ez, dv);
    float tt = fmaf(-0.5f, el2, dv);
    float sq = tt * tt * __builtin_amdgcn_rcpf(el2);
    float best = isedge ? sq : INFINITY;
#pragma unroll
    for (int lvl = 1; lvl <= 32; lvl <<= 1) {
      best = fminf(best, __shfl_xor(best, lvl));
    }
    if (wl == 0) out[(size_t)b * N + (tile * QPB + q * GROUPS + g)] = best;
  }
}

extern "C" void kernel_launch(void* const* d_in, const int* in_sizes, int n_in,
                              void* d_out, int out_size, void* d_ws, size_t ws_size,
                              hipStream_t stream) {
  const float* points = (const float*)d_in[0];
  const float* spoints = (const float*)d_in[1];
  float* out = (float*)d_out;
  (void)in_sizes; (void)n_in; (void)out_size; (void)d_ws; (void)ws_size;
  voroloss_kernel<<<dim3(B * (N / QPB)), dim3(BLOCK), 0, stream>>>(points, spoints, out);
}

// Round 10
// 98.774 us; speedup vs baseline: 1.3046x; 1.0921x over previous
//
#include <hip/hip_runtime.h>
#include <math.h>

namespace {
constexpr int B = 2;
constexpr int N = 16384;
constexpr int M = 4096;
constexpr int K = 11;
constexpr int TQ = 64;              // lanes per query group = full wave
constexpr int BLOCK = 512;          // 8 waves/block
constexpr int Q = 8;                // queries per wave
constexpr int GROUPS = BLOCK / TQ;  // 8 waves/block
constexpr int QPB = GROUPS * Q;     // 64 queries/block -> 512 blocks = 2/CU
constexpr int S = M / TQ;           // 64 candidates per lane
constexpr int CAP = 64;             // per-query collect capacity
}

// Shifted squared distance: |s|^2 - 2 p.s (order preserving). MUST be the
// identical op sequence in phases A/B/C for bit-exact threshold agreement.
__device__ __forceinline__ float d2of(const float4 s, float m2x, float m2y, float m2z) {
  return fmaf(m2x, s.x, fmaf(m2y, s.y, fmaf(m2z, s.z, s.w)));
}

__global__ __launch_bounds__(BLOCK, 4) void voroloss_kernel(
    const float* __restrict__ points,    // [B, N, 3]
    const float* __restrict__ spoints,   // [B, M, 3]
    float* __restrict__ out)             // [B, N]
{
  __shared__ float4 s4[M];                  // (x,y,z,|s|^2) 64 KiB
  __shared__ unsigned short buf[QPB][CAP];  // candidate idx 8 KiB

  const int blocks_per_batch = N / QPB;     // 256
  const int b = blockIdx.x / blocks_per_batch;
  const int tile = blockIdx.x % blocks_per_batch;
  const int tid = (int)threadIdx.x;
  const int wl = tid & 63;                  // lane in wave = lane in group
  const int g = tid >> 6;                   // wave id = group id

  const float* sp = spoints + (size_t)b * M * 3;
  for (int j = tid; j < M; j += BLOCK) {
    float x = sp[j * 3 + 0], y = sp[j * 3 + 1], z = sp[j * 3 + 2];
    s4[j] = make_float4(x, y, z, x * x + y * y + z * z);
  }
  __syncthreads();

  float m2x[Q], m2y[Q], m2z[Q];
#pragma unroll
  for (int q = 0; q < Q; ++q) {
    int n = tile * QPB + q * GROUPS + g;    // uniform per wave
    m2x[q] = -2.0f * points[((size_t)b * N + n) * 3 + 0];
    m2y[q] = -2.0f * points[((size_t)b * N + n) * 3 + 1];
    m2z[q] = -2.0f * points[((size_t)b * N + n) * 3 + 2];
  }

  // ---- Phase A: per-lane min over strided subset j = i*64 + wl.
  float t0[Q];
#pragma unroll
  for (int q = 0; q < Q; ++q) t0[q] = INFINITY;

  for (int i0 = 0; i0 < S; i0 += 8) {
    float4 sv[8];
#pragma unroll
    for (int c = 0; c < 8; ++c) sv[c] = s4[(i0 + c) * TQ + wl];
#pragma unroll
    for (int q = 0; q < Q; ++q) {
#pragma unroll
      for (int c = 0; c < 8; ++c) {
        t0[q] = fminf(t0[q], d2of(sv[c], m2x[q], m2y[q], m2z[q]));
      }
    }
  }

  // ---- theta: 11th smallest of 32 pair-minima per query (provable upper
  // bound on true 11th smallest). Dual-query: lower half-wave sorts query qp,
  // upper half sorts qp+1 (xor j<=16 never crosses the half boundary).
  // Direction bools are lane-only -> hoisted once (compiler: SGPR lane masks).
  const int h = wl & 31;
  bool km[15];
  {
    int st = 0;
#pragma unroll
    for (int k = 2; k <= 32; k <<= 1) {
#pragma unroll
      for (int j = 16; j > 0; j >>= 1) {
        if (j < k) {
          bool up = (h & k) == 0;
          bool lower = (h & j) == 0;
          km[st++] = (lower == up);
        }
      }
    }
  }
  float theta[Q];
#pragma unroll
  for (int qp = 0; qp < Q; qp += 2) {
    float a0 = fminf(t0[qp],     __shfl_xor(t0[qp],     32));
    float a1 = fminf(t0[qp + 1], __shfl_xor(t0[qp + 1], 32));
    float x = (wl < 32) ? a0 : a1;
    int st = 0;
#pragma unroll
    for (int k = 2; k <= 32; k <<= 1) {
#pragma unroll
      for (int j = 16; j > 0; j >>= 1) {
        if (j < k) {
          float o = __shfl_xor(x, j);
          x = km[st++] ? fminf(x, o) : fmaxf(x, o);
        }
      }
    }
    theta[qp]     = __shfl(x, 10, 64);
    theta[qp + 1] = __shfl(x, 42, 64);
  }

  // ---- Phase B: rescan; wave-cooperative compaction with SGPR counters.
  // No atomics: this wave exclusively owns its Q queries' buffers.
  int cnt[Q];
#pragma unroll
  for (int q = 0; q < Q; ++q) cnt[q] = 0;

  for (int i0 = 0; i0 < S; i0 += 8) {
    float4 sv[8];
#pragma unroll
    for (int c = 0; c < 8; ++c) sv[c] = s4[(i0 + c) * TQ + wl];
#pragma unroll
    for (int q = 0; q < Q; ++q) {
      const int qq = q * GROUPS + g;
#pragma unroll
      for (int c = 0; c < 8; ++c) {
        float d = d2of(sv[c], m2x[q], m2y[q], m2z[q]);
        bool hit = d <= theta[q];
        unsigned long long mask = __ballot(hit);
        if (mask != 0) {                    // uniform branch, ~20% taken
          int base = cnt[q];
          if (hit) {
            unsigned int lo = __builtin_amdgcn_mbcnt_lo((unsigned int)mask, 0u);
            unsigned int pr = __builtin_amdgcn_mbcnt_hi((unsigned int)(mask >> 32), lo);
            int pos = base + (int)pr;
            if (pos < CAP) buf[qq][pos] = (unsigned short)((i0 + c) * TQ + wl);
          }
          cnt[q] = base + (int)__popcll(mask);
        }
      }
    }
  }

  // ---- Phase C: exact selection (lex (d2,idx) = stable top_k). Lane wl owns
  // slot wl; ranks via shfl broadcast of each entry.
#pragma unroll
  for (int q = 0; q < Q; ++q) {
    const int qq = q * GROUPS + g;
    int c = cnt[q];
    c = c < CAP ? c : CAP;

    bool v = wl < c;
    int ide = (int)buf[qq][v ? wl : 0];
    float4 se = s4[ide];
    float d2e = v ? d2of(se, m2x[q], m2y[q], m2z[q]) : INFINITY;
    ide = v ? ide : 0x7fffffff;

    int rank = 0;
    for (int f = 0; f < c; ++f) {
      float df = __shfl(d2e, f, 64);
      int jf = __shfl(ide, f, 64);
      rank += ((df < d2e) || (df == d2e && jf < ide)) ? 1 : 0;
    }

    // center = rank 0 (exists, unique): ballot + shfl its index.
    unsigned long long cb = __ballot(v && rank == 0);
    int cl = (int)__builtin_ctzll(cb);
    int ci = __shfl(ide, cl, 64);
    float4 cc = s4[ci];
    float px = -0.5f * m2x[q], py = -0.5f * m2y[q], pz = -0.5f * m2z[q];
    float vx = px - cc.x, vy = py - cc.y, vz = pz - cc.z;

    // edges = ranks 1..10 (exactly 10 since c >= 11).
    // sq = (dot(v,e) - |e|^2/2)^2 / |e|^2
    bool isedge = v && (rank >= 1) && (rank <= 10);
    float ex = se.x - cc.x, ey = se.y - cc.y, ez = se.z - cc.z;
    float el2 = ex * ex;
    el2 = fmaf(ey, ey, el2);
    el2 = fmaf(ez, ez, el2);
    float dv = vx * ex;
    dv = fmaf(vy, ey, dv);
    dv = fmaf(vz, ez, dv);
    float tt = fmaf(-0.5f, el2, dv);
    float sq = tt * tt * __builtin_amdgcn_rcpf(el2);
    float best = isedge ? sq : INFINITY;
#pragma unroll
    for (int lvl = 1; lvl <= 32; lvl <<= 1) {
      best = fminf(best, __shfl_xor(best, lvl));
    }
    if (wl == 0) out[(size_t)b * N + (tile * QPB + q * GROUPS + g)] = best;
  }
}

extern "C" void kernel_launch(void* const* d_in, const int* in_sizes, int n_in,
                              void* d_out, int out_size, void* d_ws, size_t ws_size,
                              hipStream_t stream) {
  const float* points = (const float*)d_in[0];
  const float* spoints = (const float*)d_in[1];
  float* out = (float*)d_out;
  (void)in_sizes; (void)n_in; (void)out_size; (void)d_ws; (void)ws_size;
  voroloss_kernel<<<dim3(B * (N / QPB)), dim3(BLOCK), 0, stream>>>(points, spoints, out);
}

// Round 11
// 95.117 us; speedup vs baseline: 1.3548x; 1.0384x over previous
//
#include <hip/hip_runtime.h>
#include <math.h>

namespace {
constexpr int B = 2;
constexpr int N = 16384;
constexpr int M = 4096;
constexpr int K = 11;
constexpr int TQ = 64;              // lanes per query group = full wave
constexpr int BLOCK = 1024;         // 16 waves/block
constexpr int Q = 4;                // queries per wave
constexpr int GROUPS = BLOCK / TQ;  // 16 waves/block
constexpr int QPB = GROUPS * Q;     // 64 queries/block -> 512 blocks = 2/CU
constexpr int S = M / TQ;           // 64 candidates per lane
constexpr int CAP = 64;             // per-query collect capacity
}

// Shifted squared distance: |s|^2 - 2 p.s (order preserving). MUST be the
// identical op sequence in phases A/B/C for bit-exact threshold agreement.
__device__ __forceinline__ float d2of(const float4 s, float m2x, float m2y, float m2z) {
  return fmaf(m2x, s.x, fmaf(m2y, s.y, fmaf(m2z, s.z, s.w)));
}

// 72.25 KiB LDS/block, 64 VGPR cap -> 2 blocks/CU, 32 waves/CU = 8 waves/SIMD
__global__ __launch_bounds__(BLOCK, 8) void voroloss_kernel(
    const float* __restrict__ points,    // [B, N, 3]
    const float* __restrict__ spoints,   // [B, M, 3]
    float* __restrict__ out)             // [B, N]
{
  __shared__ float4 s4[M];                  // (x,y,z,|s|^2) 64 KiB
  __shared__ unsigned short buf[QPB][CAP];  // candidate idx 8 KiB

  const int blocks_per_batch = N / QPB;     // 256
  const int b = blockIdx.x / blocks_per_batch;
  const int tile = blockIdx.x % blocks_per_batch;
  const int tid = (int)threadIdx.x;
  const int wl = tid & 63;                  // lane in wave = lane in group
  const int g = tid >> 6;                   // wave id = group id (0..15)

  const float* sp = spoints + (size_t)b * M * 3;
  for (int j = tid; j < M; j += BLOCK) {
    float x = sp[j * 3 + 0], y = sp[j * 3 + 1], z = sp[j * 3 + 2];
    s4[j] = make_float4(x, y, z, x * x + y * y + z * z);
  }
  __syncthreads();

  float m2x[Q], m2y[Q], m2z[Q];
#pragma unroll
  for (int q = 0; q < Q; ++q) {
    int n = tile * QPB + q * GROUPS + g;    // uniform per wave
    m2x[q] = -2.0f * points[((size_t)b * N + n) * 3 + 0];
    m2y[q] = -2.0f * points[((size_t)b * N + n) * 3 + 1];
    m2z[q] = -2.0f * points[((size_t)b * N + n) * 3 + 2];
  }

  // ---- Phase A: per-lane min over strided subset j = i*64 + wl.
  float t0[Q];
#pragma unroll
  for (int q = 0; q < Q; ++q) t0[q] = INFINITY;

  for (int i0 = 0; i0 < S; i0 += 4) {
    float4 sv[4];
#pragma unroll
    for (int c = 0; c < 4; ++c) sv[c] = s4[(i0 + c) * TQ + wl];
#pragma unroll
    for (int q = 0; q < Q; ++q) {
#pragma unroll
      for (int c = 0; c < 4; ++c) {
        t0[q] = fminf(t0[q], d2of(sv[c], m2x[q], m2y[q], m2z[q]));
      }
    }
  }

  // ---- theta: 11th smallest of 32 pair-minima per query (provable upper
  // bound on true 11th smallest). Dual-query: lower half-wave sorts qp,
  // upper half sorts qp+1 (xor j<=16 never crosses the half boundary).
  const int h = wl & 31;
  bool km[15];
  {
    int st = 0;
#pragma unroll
    for (int k = 2; k <= 32; k <<= 1) {
#pragma unroll
      for (int j = 16; j > 0; j >>= 1) {
        if (j < k) {
          bool up = (h & k) == 0;
          bool lower = (h & j) == 0;
          km[st++] = (lower == up);
        }
      }
    }
  }
  float theta[Q];
#pragma unroll
  for (int qp = 0; qp < Q; qp += 2) {
    float a0 = fminf(t0[qp],     __shfl_xor(t0[qp],     32));
    float a1 = fminf(t0[qp + 1], __shfl_xor(t0[qp + 1], 32));
    float x = (wl < 32) ? a0 : a1;
    int st = 0;
#pragma unroll
    for (int k = 2; k <= 32; k <<= 1) {
#pragma unroll
      for (int j = 16; j > 0; j >>= 1) {
        if (j < k) {
          float o = __shfl_xor(x, j);
          x = km[st++] ? fminf(x, o) : fmaxf(x, o);
        }
      }
    }
    theta[qp]     = __shfl(x, 10, 64);
    theta[qp + 1] = __shfl(x, 42, 64);
  }

  // ---- Phase B: rescan; wave-cooperative compaction, SGPR counters, no
  // atomics (this wave exclusively owns its Q queries' buffers).
  int cnt[Q];
#pragma unroll
  for (int q = 0; q < Q; ++q) cnt[q] = 0;

  for (int i0 = 0; i0 < S; i0 += 4) {
    float4 sv[4];
#pragma unroll
    for (int c = 0; c < 4; ++c) sv[c] = s4[(i0 + c) * TQ + wl];
#pragma unroll
    for (int q = 0; q < Q; ++q) {
      const int qq = q * GROUPS + g;
#pragma unroll
      for (int c = 0; c < 4; ++c) {
        float d = d2of(sv[c], m2x[q], m2y[q], m2z[q]);
        bool hit = d <= theta[q];
        unsigned long long mask = __ballot(hit);
        if (mask != 0) {                    // uniform branch, ~20% taken
          int base = cnt[q];
          if (hit) {
            unsigned int lo = __builtin_amdgcn_mbcnt_lo((unsigned int)mask, 0u);
            unsigned int pr = __builtin_amdgcn_mbcnt_hi((unsigned int)(mask >> 32), lo);
            int pos = base + (int)pr;
            if (pos < CAP) buf[qq][pos] = (unsigned short)((i0 + c) * TQ + wl);
          }
          cnt[q] = base + (int)__popcll(mask);
        }
      }
    }
  }

  // ---- Phase C: exact selection (lex (d2,idx) = stable top_k). Lane wl owns
  // slot wl; ranks via independent shfl broadcasts (no dependent chains).
#pragma unroll
  for (int q = 0; q < Q; ++q) {
    const int qq = q * GROUPS + g;
    int c = cnt[q];
    c = c < CAP ? c : CAP;

    bool v = wl < c;
    int ide = (int)buf[qq][v ? wl : 0];
    float4 se = s4[ide];
    float d2e = v ? d2of(se, m2x[q], m2y[q], m2z[q]) : INFINITY;
    ide = v ? ide : 0x7fffffff;

    int rank = 0;
    for (int f = 0; f < c; ++f) {
      float df = __shfl(d2e, f, 64);
      int jf = __shfl(ide, f, 64);
      rank += ((df < d2e) || (df == d2e && jf < ide)) ? 1 : 0;
    }

    // center = rank 0 (exists, unique): ballot + shfl its index.
    unsigned long long cb = __ballot(v && rank == 0);
    int cl = (int)__builtin_ctzll(cb);
    int ci = __shfl(ide, cl, 64);
    float4 cc = s4[ci];
    float px = -0.5f * m2x[q], py = -0.5f * m2y[q], pz = -0.5f * m2z[q];
    float vx = px - cc.x, vy = py - cc.y, vz = pz - cc.z;

    // edges = ranks 1..10 (exactly 10 since c >= 11).
    // sq = (dot(v,e) - |e|^2/2)^2 / |e|^2
    bool isedge = v && (rank >= 1) && (rank <= 10);
    float ex = se.x - cc.x, ey = se.y - cc.y, ez = se.z - cc.z;
    float el2 = ex * ex;
    el2 = fmaf(ey, ey, el2);
    el2 = fmaf(ez, ez, el2);
    float dv = vx * ex;
    dv = fmaf(vy, ey, dv);
    dv = fmaf(vz, ez, dv);
    float tt = fmaf(-0.5f, el2, dv);
    float sq = tt * tt * __builtin_amdgcn_rcpf(el2);
    float best = isedge ? sq : INFINITY;
#pragma unroll
    for (int lvl = 1; lvl <= 32; lvl <<= 1) {
      best = fminf(best, __shfl_xor(best, lvl));
    }
    if (wl == 0) out[(size_t)b * N + (tile * QPB + q * GROUPS + g)] = best;
  }
}

extern "C" void kernel_launch(void* const* d_in, const int* in_sizes, int n_in,
                              void* d_out, int out_size, void* d_ws, size_t ws_size,
                              hipStream_t stream) {
  const float* points = (const float*)d_in[0];
  const float* spoints = (const float*)d_in[1];
  float* out = (float*)d_out;
  (void)in_sizes; (void)n_in; (void)out_size; (void)d_ws; (void)ws_size;
  voroloss_kernel<<<dim3(B * (N / QPB)), dim3(BLOCK), 0, stream>>>(points, spoints, out);
}